// Round 9
// baseline (126.240 us; speedup 1.0000x reference)
//
#include <hip/hip_runtime.h>
#include <math.h>

#define NN 512
#define FF 64
#define HH 4

// ---------------- ws layout (floats) ----------------
// dinv : [512]               off 0
// cvec : [512]               off 512
// T    : [B*H*N]   = 8192    off 1024
// q_t  : [B*H*N*F] = 2097152 off 9216
// k_t  : [B*H*N*F] = 2097152 off 2106368   ([bh][i][f])

// S1: q+k projection. 256 blocks (4b x 64 itiles of 8 rows) x 512 thr.
// Thread tile 2 rows x 4 cols; x staged in LDS (broadcast reads), W via
// coalesced global float4 (off the LDS pipe). Side jobs: b==0 blocks do
// dinv rows; blk<16 zero T; blk 0 zeros cvec.
__global__ __launch_bounds__(512) void k_s1(const float* __restrict__ x,
                                            const float* __restrict__ Wq,
                                            const float* __restrict__ bq,
                                            const float* __restrict__ Wk,
                                            const float* __restrict__ bk,
                                            const float* __restrict__ adj,
                                            float* __restrict__ q_t,
                                            float* __restrict__ k_t,
                                            float* __restrict__ dinv,
                                            float* __restrict__ T,
                                            float* __restrict__ cvec) {
    __shared__ float xl[8][64];
    int blk = blockIdx.x, tid = threadIdx.x;
    int wave = tid >> 6, lane = tid & 63;
    int b = blk >> 6, itile = blk & 63;
    int i0 = itile * 8;

    xl[tid >> 6][tid & 63] = x[((long)b * NN + i0 + (tid >> 6)) * FF + (tid & 63)];

    if (b == 0) {   // blk < 64: dinv for row i0+wave
        int gi = i0 + wave;
        float acc = 0.f;
#pragma unroll
        for (int k = 0; k < 8; ++k) acc += adj[(long)gi * NN + k * 64 + lane];
        for (int o = 32; o > 0; o >>= 1) acc += __shfl_xor(acc, o);
        if (lane == 0) dinv[gi] = 1.0f / sqrtf(acc + 1.0f);
    }
    if (blk < 16) T[blk * 512 + tid] = 0.f;
    if (blk == 0) cvec[tid] = 0.f;
    __syncthreads();

    int rg = tid >> 7;            // 0..3 -> rows i0+rg*2, i0+rg*2+1
    int cg = tid & 127;           // 0..127 -> global col4 = cg*4 (0..511)
    int col4 = cg * 4;
    int isK = col4 >> 8;          // cols 256..511 are k
    int colq = col4 & 255;
    const float* W = isK ? Wk : Wq;
    const float* bias = isK ? bk : bq;
    float4 bv = *(const float4*)(bias + colq);
    float4 a0 = bv, a1 = bv;
    const float* xr0 = &xl[rg * 2][0];
    const float* xr1 = &xl[rg * 2 + 1][0];
#pragma unroll 8
    for (int cc = 0; cc < 64; ++cc) {
        float4 w = *(const float4*)(W + cc * 256 + colq);
        float x0 = xr0[cc], x1 = xr1[cc];
        a0.x = fmaf(x0, w.x, a0.x); a0.y = fmaf(x0, w.y, a0.y);
        a0.z = fmaf(x0, w.z, a0.z); a0.w = fmaf(x0, w.w, a0.w);
        a1.x = fmaf(x1, w.x, a1.x); a1.y = fmaf(x1, w.y, a1.y);
        a1.z = fmaf(x1, w.z, a1.z); a1.w = fmaf(x1, w.w, a1.w);
    }
    int h = colq >> 6, f = colq & 63;   // f % 4 == 0
    float* dst = (isK ? k_t : q_t) + ((long)(b * HH + h) * NN + (i0 + rg * 2)) * FF + f;
    *(float4*)dst = a0;
    *(float4*)(dst + FF) = a1;
}

// S2: QK^T GEMM + softmax + noradj weighting -> T (+cvec).
// 256 blocks (16 bh x 16 itiles of 32 rows) x 512 thr.
// Thread (ig=tid&7 -> 4 rows, jg=tid>>3 -> 8 cols) owns acc[4][8].
// Per k4-step: 12 LDS b128 reads per 128 FMAs (2-way-conflict-free mapping).
__global__ __launch_bounds__(512) void k_s2(const float* __restrict__ q_t,
                                            const float* __restrict__ k_t,
                                            const float* __restrict__ adj,
                                            const float* __restrict__ dinv,
                                            float* __restrict__ T,
                                            float* __restrict__ cvec) {
    __shared__ float ql[32 * 68];      // 32 q rows, 68-float stride (bank-spread)
    __shared__ float kl[512 * 16];     // k chunk, xor-swizzled f4 slots
    __shared__ float redm[8][32];
    __shared__ float redz[8][32];
    int blk = blockIdx.x, tid = threadIdx.x;
    int bh = blk >> 4, itile = blk & 15;
    int i0 = itile * 32;
    int wv = tid >> 6, lane = tid & 63;
    int ig = tid & 7, jg = tid >> 3;

    {   // stage q: 32 rows x 16 f4 = 512 f4, one per thread
        int r = tid >> 4, c4 = tid & 15;
        *(float4*)&ql[r * 68 + c4 * 4] =
            *(const float4*)(q_t + ((long)bh * NN + i0 + r) * FF + c4 * 4);
    }

    float acc[4][8];
#pragma unroll
    for (int ii = 0; ii < 4; ++ii)
#pragma unroll
        for (int jj = 0; jj < 8; ++jj) acc[ii][jj] = 0.f;

    const float* kb = k_t + (long)bh * NN * FF;
#pragma unroll
    for (int cc = 0; cc < 4; ++cc) {
        // stage k chunk: 512 rows x 4 f4 = 2048 f4, 4 per thread
#pragma unroll
        for (int w = 0; w < 4; ++w) {
            int v = w * 512 + tid;
            int row = v >> 2, c4 = v & 3;
            int slot = c4 ^ ((row >> 3) & 3);
            *(float4*)&kl[row * 16 + slot * 4] =
                *(const float4*)(kb + (long)row * FF + cc * 16 + c4 * 4);
        }
        __syncthreads();
#pragma unroll
        for (int k4 = 0; k4 < 4; ++k4) {
            float4 qf[4], kf[8];
#pragma unroll
            for (int ii = 0; ii < 4; ++ii)
                qf[ii] = *(const float4*)&ql[(ig * 4 + ii) * 68 + cc * 16 + k4 * 4];
#pragma unroll
            for (int jj = 0; jj < 8; ++jj) {
                int j = jg * 8 + jj;
                int slot = k4 ^ ((j >> 3) & 3);
                kf[jj] = *(const float4*)&kl[j * 16 + slot * 4];
            }
#pragma unroll
            for (int ii = 0; ii < 4; ++ii)
#pragma unroll
                for (int jj = 0; jj < 8; ++jj) {
                    acc[ii][jj] = fmaf(qf[ii].x, kf[jj].x, acc[ii][jj]);
                    acc[ii][jj] = fmaf(qf[ii].y, kf[jj].y, acc[ii][jj]);
                    acc[ii][jj] = fmaf(qf[ii].z, kf[jj].z, acc[ii][jj]);
                    acc[ii][jj] = fmaf(qf[ii].w, kf[jj].w, acc[ii][jj]);
                }
        }
        __syncthreads();
    }

    // softmax: row max (reduce over jg = lane bits 3..5, then 8 waves)
    const float scale = 0.125f;   // 1/sqrt(64)
    float m[4], Zi[4];
#pragma unroll
    for (int ii = 0; ii < 4; ++ii) {
        float v = acc[ii][0];
#pragma unroll
        for (int jj = 1; jj < 8; ++jj) v = fmaxf(v, acc[ii][jj]);
        v = fmaxf(v, __shfl_xor(v, 8));
        v = fmaxf(v, __shfl_xor(v, 16));
        v = fmaxf(v, __shfl_xor(v, 32));
        if (lane < 8) redm[wv][ig * 4 + ii] = v;
    }
    __syncthreads();
#pragma unroll
    for (int ii = 0; ii < 4; ++ii) {
        int row = ig * 4 + ii;
        float v = redm[0][row];
#pragma unroll
        for (int w = 1; w < 8; ++w) v = fmaxf(v, redm[w][row]);
        m[ii] = v;
    }
#pragma unroll
    for (int ii = 0; ii < 4; ++ii) {
        float z = 0.f;
#pragma unroll
        for (int jj = 0; jj < 8; ++jj) {
            float p = expf((acc[ii][jj] - m[ii]) * scale);
            acc[ii][jj] = p;
            z += p;
        }
        z += __shfl_xor(z, 8);
        z += __shfl_xor(z, 16);
        z += __shfl_xor(z, 32);
        if (lane < 8) redz[wv][ig * 4 + ii] = z;
    }
    __syncthreads();
#pragma unroll
    for (int ii = 0; ii < 4; ++ii) {
        int row = ig * 4 + ii;
        float z = redz[0][row];
#pragma unroll
        for (int w = 1; w < 8; ++w) z += redz[w][row];
        Zi[ii] = 1.0f / z;
    }

    // weighting + column partial sums (adj direct from global)
    float cs[8], cw[8];
#pragma unroll
    for (int jj = 0; jj < 8; ++jj) { cs[jj] = 0.f; cw[jj] = 0.f; }
#pragma unroll
    for (int ii = 0; ii < 4; ++ii) {
        int gi = i0 + ig * 4 + ii;
        float di = dinv[gi];
        float av[8];
        *(float4*)&av[0] = *(const float4*)(adj + (long)gi * NN + jg * 8);
        *(float4*)&av[4] = *(const float4*)(adj + (long)gi * NN + jg * 8 + 4);
        float dz = di * Zi[ii];
#pragma unroll
        for (int jj = 0; jj < 8; ++jj) {
            int j = jg * 8 + jj;
            float a = av[jj] + (gi == j ? 1.f : 0.f);
            cs[jj] = fmaf(dz * a, acc[ii][jj], cs[jj]);
            cw[jj] = fmaf(di, a, cw[jj]);
        }
    }
    // reduce over ig (lane bits 0..2)
#pragma unroll
    for (int jj = 0; jj < 8; ++jj) {
        float v = cs[jj];
        v += __shfl_xor(v, 1);
        v += __shfl_xor(v, 2);
        v += __shfl_xor(v, 4);
        cs[jj] = v;
    }
    if (bh == 0) {
#pragma unroll
        for (int jj = 0; jj < 8; ++jj) {
            float w = cw[jj];
            w += __shfl_xor(w, 1);
            w += __shfl_xor(w, 2);
            w += __shfl_xor(w, 4);
            cw[jj] = w;
        }
    }
    if (ig == 0) {
#pragma unroll
        for (int jj = 0; jj < 8; ++jj) {
            int j = jg * 8 + jj;
            atomicAdd(&T[bh * NN + j], cs[jj] * dinv[j]);
        }
        if (bh == 0) {
#pragma unroll
            for (int jj = 0; jj < 8; ++jj)
                atomicAdd(&cvec[jg * 8 + jj], cw[jj]);
        }
    }
}

// S3: fused sxd + SpMM + FC + relu, NO LDS in the main loop.
// 512 blocks (b x 128 itiles of 4 rows) x 256 thr (jc=tid>>6, f=tid&63).
// Per j: x vector load + uniform scalar loads (dinv/cvec/T/adj -> s_load,
// dual-issued with VALU) + 10 FMA. Identity + FC in epilogue.
__global__ __launch_bounds__(256) void k_s3(const float* __restrict__ x,
                                            const float* __restrict__ adj,
                                            const float* __restrict__ dinv,
                                            const float* __restrict__ cvec,
                                            const float* __restrict__ T,
                                            const float* __restrict__ Wlin,
                                            const float* __restrict__ blin,
                                            const float* __restrict__ Wfc,
                                            const float* __restrict__ bfc,
                                            float* __restrict__ out) {
    __shared__ float part[4][4][64];
    __shared__ float m_lds[4][64];
    int blk = blockIdx.x, tid = threadIdx.x;
    int b = blk >> 7, itile = blk & 127;
    int i0 = itile * 4;
    int f = tid & 63, jc = tid >> 6;

    float blf = blin[f];
    float4 wl = make_float4(Wlin[f], Wlin[64 + f], Wlin[128 + f], Wlin[192 + f]);
    const float* xb = x + (long)b * NN * FF + f;
    const float* Tb = T + (long)b * HH * NN;
    const float* ar0 = adj + (long)(i0 + 0) * NN;
    const float* ar1 = adj + (long)(i0 + 1) * NN;
    const float* ar2 = adj + (long)(i0 + 2) * NN;
    const float* ar3 = adj + (long)(i0 + 3) * NN;

    float a0 = 0.f, a1 = 0.f, a2 = 0.f, a3 = 0.f;
    int jb = jc * 128;
#pragma unroll 4
    for (int j = jb; j < jb + 128; ++j) {
        float dj = dinv[j];                        // uniform -> scalar pipe
        float S = blf * (dj * dj * cvec[j]);
        S = fmaf(wl.x, dj * Tb[j], S);
        S = fmaf(wl.y, dj * Tb[NN + j], S);
        S = fmaf(wl.z, dj * Tb[2 * NN + j], S);
        S = fmaf(wl.w, dj * Tb[3 * NN + j], S);
        float sx = xb[(long)j * FF] * S;           // per-lane vector load
        a0 = fmaf(ar0[j], sx, a0);
        a1 = fmaf(ar1[j], sx, a1);
        a2 = fmaf(ar2[j], sx, a2);
        a3 = fmaf(ar3[j], sx, a3);
    }
    part[jc][0][f] = a0; part[jc][1][f] = a1;
    part[jc][2][f] = a2; part[jc][3][f] = a3;
    __syncthreads();

    // wave r combines row r, adds identity term sx(j=i0+r), scales by dinv
    int r = jc;
    int gi = i0 + r;
    float djq = dinv[gi];
    float Sq = blf * (djq * djq * cvec[gi]);
    Sq = fmaf(wl.x, djq * Tb[gi], Sq);
    Sq = fmaf(wl.y, djq * Tb[NN + gi], Sq);
    Sq = fmaf(wl.z, djq * Tb[2 * NN + gi], Sq);
    Sq = fmaf(wl.w, djq * Tb[3 * NN + gi], Sq);
    float sx_id = xb[(long)gi * FF] * Sq;
    m_lds[r][f] = (part[0][r][f] + part[1][r][f] + part[2][r][f] + part[3][r][f]
                   + sx_id) * djq;
    __syncthreads();

    float o = bfc[f];
#pragma unroll
    for (int cc = 0; cc < 64; ++cc)
        o = fmaf(m_lds[r][cc], Wfc[cc * FF + f], o);
    out[((long)b * NN + gi) * FF + f] = fmaxf(o, 0.f);
}

extern "C" void kernel_launch(void* const* d_in, const int* in_sizes, int n_in,
                              void* d_out, int out_size, void* d_ws, size_t ws_size,
                              hipStream_t stream) {
    const float* x    = (const float*)d_in[0];
    const float* adj  = (const float*)d_in[1];
    const float* Wq   = (const float*)d_in[2];
    const float* bq   = (const float*)d_in[3];
    const float* Wk   = (const float*)d_in[4];
    const float* bk   = (const float*)d_in[5];
    const float* Wlin = (const float*)d_in[6];
    const float* blin = (const float*)d_in[7];
    const float* Wfc  = (const float*)d_in[8];
    const float* bfc  = (const float*)d_in[9];
    float* out = (float*)d_out;

    float* ws   = (float*)d_ws;
    float* dinv = ws;                 // 512
    float* cvec = ws + 512;           // 512
    float* T    = ws + 1024;          // 8192
    float* q_t  = ws + 9216;          // 2097152
    float* k_t  = ws + 2106368;       // 2097152

    k_s1<<<dim3(256), dim3(512), 0, stream>>>(x, Wq, bq, Wk, bk, adj, q_t, k_t, dinv, T, cvec);
    k_s2<<<dim3(256), dim3(512), 0, stream>>>(q_t, k_t, adj, dinv, T, cvec);
    k_s3<<<dim3(512), dim3(256), 0, stream>>>(x, adj, dinv, cvec, T, Wlin, blin, Wfc, bfc, out);
}

// Round 10
// 109.678 us; speedup vs baseline: 1.1510x; 1.1510x over previous
//
#include <hip/hip_runtime.h>
#include <math.h>

#define NN 512
#define FF 64
#define HH 4

// ---------------- ws layout (floats) ----------------
// dinv : [512]               off 0
// cvec : [512]               off 512
// T    : [B*H*N]   = 8192    off 1024
// q_t  : [B*H*N*F] = 2097152 off 9216
// kT   : [B*H*F*N] = 2097152 off 2106368

// S1: q/k projection (1024 blocks x 256 thr, 4-row tiles, q XOR k per block)
//     + side jobs: dinv rows (blocks 0-511, wave 0), zero T (blocks 0-127,
//     wave 1), zero cvec (blocks 0-7, wave 2).   [R4-measured best]
__global__ __launch_bounds__(256) void k_s1(const float* __restrict__ x,
                                            const float* __restrict__ Wq,
                                            const float* __restrict__ bq,
                                            const float* __restrict__ Wk,
                                            const float* __restrict__ bk,
                                            const float* __restrict__ adj,
                                            float* __restrict__ q_t,
                                            float* __restrict__ kT,
                                            float* __restrict__ dinv,
                                            float* __restrict__ T,
                                            float* __restrict__ cvec) {
    __shared__ float x_lds[4][64];
    int blk = blockIdx.x, tid = threadIdx.x;
    int wave = tid >> 6, lane = tid & 63;

    if (blk < 512 && wave == 0) {
        float acc = 0.f;
#pragma unroll
    for (int k = 0; k < 8; ++k) acc += adj[(long)blk * NN + k * 64 + lane];
        for (int o = 32; o > 0; o >>= 1) acc += __shfl_xor(acc, o);
        if (lane == 0) dinv[blk] = 1.0f / sqrtf(acc + 1.0f);
    }
    if (blk < 128 && wave == 1) T[blk * 64 + lane] = 0.f;
    if (blk < 8 && wave == 2) cvec[blk * 64 + lane] = 0.f;

    int b = blk >> 8, rest = blk & 255, isK = rest >> 7, itile = rest & 127;
    int i0 = itile * 4;
    x_lds[tid >> 6][tid & 63] = x[((long)b * NN + i0 + (tid >> 6)) * FF + (tid & 63)];
    __syncthreads();
    const float* W = isK ? Wk : Wq;
    float bv = (isK ? bk : bq)[tid];
    float a0 = bv, a1 = bv, a2 = bv, a3 = bv;
    for (int cc = 0; cc < 64; ++cc) {
        float w = W[cc * 256 + tid];
        a0 = fmaf(x_lds[0][cc], w, a0);
        a1 = fmaf(x_lds[1][cc], w, a1);
        a2 = fmaf(x_lds[2][cc], w, a2);
        a3 = fmaf(x_lds[3][cc], w, a3);
    }
    int h = tid >> 6, f = tid & 63;
    int bh = b * HH + h;
    if (!isK) {
        long base = ((long)bh * NN + i0) * FF + f;
        q_t[base] = a0; q_t[base + FF] = a1;
        q_t[base + 2 * FF] = a2; q_t[base + 3 * FF] = a3;
    } else {
        long base = ((long)bh * FF + f) * NN + i0;  // i0%4==0 -> 16B aligned
        *(float4*)(kT + base) = make_float4(a0, a1, a2, a3);
    }
}

// S2: scores -> softmax -> noradj weighting -> atomicAdd into T (+cvec).
//     1024 blocks x 256 thr, 8 i-rows each, 2 j per thread.  [R4-measured
//     best; only delta: __expf]
__global__ __launch_bounds__(256) void k_s2(const float* __restrict__ q_t,
                                            const float* __restrict__ kT,
                                            const float* __restrict__ adj,
                                            const float* __restrict__ dinv,
                                            float* __restrict__ T,
                                            float* __restrict__ cvec) {
    __shared__ float q_lds[8][64];
    __shared__ float red[8][4];
    __shared__ float red2[8][4];
    int blk = blockIdx.x, tid = threadIdx.x;
    int itile = blk & 63, h = (blk >> 6) & 3, b = blk >> 8;
    int bh = b * HH + h, i0 = itile * 8;
    int wv = tid >> 6, lane = tid & 63;
#pragma unroll
    for (int k = 0; k < 2; ++k) {
        int idx = k * 256 + tid;
        q_lds[idx >> 6][idx & 63] =
            q_t[((long)bh * NN + i0 + (idx >> 6)) * FF + (idx & 63)];
    }
    __syncthreads();
    int j0 = tid, j1 = tid + 256;
    const float* kb = kT + (long)bh * FF * NN;
    float s0[8], s1[8];
#pragma unroll
    for (int r = 0; r < 8; ++r) { s0[r] = 0.f; s1[r] = 0.f; }
#pragma unroll 2
    for (int f4 = 0; f4 < 64; f4 += 4) {
        float kv0[4], kv1[4];
#pragma unroll
        for (int u = 0; u < 4; ++u) {
            kv0[u] = kb[(f4 + u) * NN + j0];
            kv1[u] = kb[(f4 + u) * NN + j1];
        }
#pragma unroll
        for (int r = 0; r < 8; ++r) {
            float4 qv = *(const float4*)&q_lds[r][f4];
            s0[r] = fmaf(qv.x, kv0[0], s0[r]);
            s0[r] = fmaf(qv.y, kv0[1], s0[r]);
            s0[r] = fmaf(qv.z, kv0[2], s0[r]);
            s0[r] = fmaf(qv.w, kv0[3], s0[r]);
            s1[r] = fmaf(qv.x, kv1[0], s1[r]);
            s1[r] = fmaf(qv.y, kv1[1], s1[r]);
            s1[r] = fmaf(qv.z, kv1[2], s1[r]);
            s1[r] = fmaf(qv.w, kv1[3], s1[r]);
        }
    }
    const float scale = 0.125f;   // 1/sqrt(64)
    float m[8];
#pragma unroll
    for (int r = 0; r < 8; ++r) {
        float v = fmaxf(s0[r], s1[r]);
        for (int o = 32; o > 0; o >>= 1) v = fmaxf(v, __shfl_xor(v, o));
        if (lane == 0) red[r][wv] = v;
    }
    __syncthreads();
#pragma unroll
    for (int r = 0; r < 8; ++r)
        m[r] = fmaxf(fmaxf(red[r][0], red[r][1]), fmaxf(red[r][2], red[r][3]));
#pragma unroll
    for (int r = 0; r < 8; ++r) {
        s0[r] = __expf((s0[r] - m[r]) * scale);
        s1[r] = __expf((s1[r] - m[r]) * scale);
        float v = s0[r] + s1[r];
        for (int o = 32; o > 0; o >>= 1) v += __shfl_xor(v, o);
        if (lane == 0) red2[r][wv] = v;
    }
    __syncthreads();
    float dj0 = dinv[j0], dj1 = dinv[j1];
    float pw0 = 0.f, pw1 = 0.f, cw0 = 0.f, cw1 = 0.f;
#pragma unroll
    for (int r = 0; r < 8; ++r) {
        float Zi = 1.0f / (red2[r][0] + red2[r][1] + red2[r][2] + red2[r][3]);
        int gi = i0 + r;
        float di = dinv[gi];
        float a0 = adj[(long)gi * NN + j0] + (gi == j0 ? 1.f : 0.f);
        float a1 = adj[(long)gi * NN + j1] + (gi == j1 ? 1.f : 0.f);
        float t0 = di * a0, t1 = di * a1;
        pw0 = fmaf(t0, s0[r] * Zi, pw0);
        pw1 = fmaf(t1, s1[r] * Zi, pw1);
        cw0 += t0;
        cw1 += t1;
    }
    atomicAdd(&T[bh * NN + j0], pw0 * dj0);
    atomicAdd(&T[bh * NN + j1], pw1 * dj1);
    if (b == 0 && h == 0) {
        atomicAdd(&cvec[j0], cw0);
        atomicAdd(&cvec[j1], cw1);
    }
}

// S3: fused sxd + SpMM + FC + relu. 1024 blocks x 256 thr, 2 rows each,
//     4-way j-split, LDS staging of per-j scalars.  [R4-measured best]
__global__ __launch_bounds__(256) void k_s3(const float* __restrict__ x,
                                            const float* __restrict__ T,
                                            const float* __restrict__ Wlin,
                                            const float* __restrict__ blin,
                                            const float* __restrict__ cvec,
                                            const float* __restrict__ adj,
                                            const float* __restrict__ dinv,
                                            const float* __restrict__ Wfc,
                                            const float* __restrict__ bfc,
                                            float* __restrict__ out) {
    __shared__ float4 u4_l[NN];      // dj*T[h][j], h=0..3
    __shared__ float  u0_l[NN];      // dj*dj*cvec[j]
    __shared__ float2 ad_l[NN];      // A[i0,j], A[i0+1,j] (identity folded)
    __shared__ float part[4][2][64];
    __shared__ float m_lds[2][64];
    __shared__ float part2[4][2][64];
    int blk = blockIdx.x, tid = threadIdx.x;
    int b = blk >> 8, itile = blk & 255;
    int i0 = itile * 2;

    for (int jj = tid; jj < NN; jj += 256) {
        float dj = dinv[jj];
        u0_l[jj] = dj * dj * cvec[jj];
        u4_l[jj] = make_float4(dj * T[(b * HH + 0) * NN + jj],
                               dj * T[(b * HH + 1) * NN + jj],
                               dj * T[(b * HH + 2) * NN + jj],
                               dj * T[(b * HH + 3) * NN + jj]);
        ad_l[jj] = make_float2(adj[(long)i0 * NN + jj] + (i0 == jj ? 1.f : 0.f),
                               adj[(long)(i0 + 1) * NN + jj] + (i0 + 1 == jj ? 1.f : 0.f));
    }
    __syncthreads();

    int f = tid & 63, jc = tid >> 6;
    int jb = jc * 128;
    float blf = blin[f];
    float4 wl = make_float4(Wlin[f], Wlin[64 + f], Wlin[128 + f], Wlin[192 + f]);
    const float* xb = x + (long)b * NN * FF + f;
    float a0 = 0.f, a1 = 0.f;
#pragma unroll 4
    for (int j = jb; j < jb + 128; ++j) {
        float xv = xb[(long)j * FF];
        float4 u = u4_l[j];
        float2 ad = ad_l[j];
        float S = blf * u0_l[j];
        S = fmaf(wl.x, u.x, S);
        S = fmaf(wl.y, u.y, S);
        S = fmaf(wl.z, u.z, S);
        S = fmaf(wl.w, u.w, S);
        float sx = xv * S;
        a0 = fmaf(ad.x, sx, a0);
        a1 = fmaf(ad.y, sx, a1);
    }
    part[jc][0][f] = a0;
    part[jc][1][f] = a1;
    __syncthreads();
    if (jc == 0) {
        m_lds[0][f] = (part[0][0][f] + part[1][0][f] + part[2][0][f] + part[3][0][f]) * dinv[i0];
        m_lds[1][f] = (part[0][1][f] + part[1][1][f] + part[2][1][f] + part[3][1][f]) * dinv[i0 + 1];
    }
    __syncthreads();
    float o0 = 0.f, o1 = 0.f;
    int c0 = jc * 16;
#pragma unroll
    for (int cc = 0; cc < 16; ++cc) {
        float w = Wfc[(c0 + cc) * FF + f];
        o0 = fmaf(m_lds[0][c0 + cc], w, o0);
        o1 = fmaf(m_lds[1][c0 + cc], w, o1);
    }
    part2[jc][0][f] = o0;
    part2[jc][1][f] = o1;
    __syncthreads();
    if (jc == 0) {
        float bb = bfc[f];
        float r0 = part2[0][0][f] + part2[1][0][f] + part2[2][0][f] + part2[3][0][f] + bb;
        float r1 = part2[0][1][f] + part2[1][1][f] + part2[2][1][f] + part2[3][1][f] + bb;
        out[((long)b * NN + i0) * FF + f]     = fmaxf(r0, 0.f);
        out[((long)b * NN + i0 + 1) * FF + f] = fmaxf(r1, 0.f);
    }
}

extern "C" void kernel_launch(void* const* d_in, const int* in_sizes, int n_in,
                              void* d_out, int out_size, void* d_ws, size_t ws_size,
                              hipStream_t stream) {
    const float* x    = (const float*)d_in[0];
    const float* adj  = (const float*)d_in[1];
    const float* Wq   = (const float*)d_in[2];
    const float* bq   = (const float*)d_in[3];
    const float* Wk   = (const float*)d_in[4];
    const float* bk   = (const float*)d_in[5];
    const float* Wlin = (const float*)d_in[6];
    const float* blin = (const float*)d_in[7];
    const float* Wfc  = (const float*)d_in[8];
    const float* bfc  = (const float*)d_in[9];
    float* out = (float*)d_out;

    float* ws   = (float*)d_ws;
    float* dinv = ws;                 // 512
    float* cvec = ws + 512;           // 512
    float* T    = ws + 1024;          // 8192
    float* q_t  = ws + 9216;          // 2097152
    float* kT   = ws + 2106368;       // 2097152

    k_s1<<<dim3(1024), dim3(256), 0, stream>>>(x, Wq, bq, Wk, bk, adj, q_t, kT, dinv, T, cvec);
    k_s2<<<dim3(1024), dim3(256), 0, stream>>>(q_t, kT, adj, dinv, T, cvec);
    k_s3<<<dim3(1024), dim3(256), 0, stream>>>(x, T, Wlin, blin, cvec, adj, dinv, Wfc, bfc, out);
}